// Round 2
// baseline (2994.980 us; speedup 1.0000x reference)
//
#include <hip/hip_runtime.h>

#define DD 256
#define KK 8192
#define HW 1024
#define NROWS 16384
#define NELEM 4194304
#define MT 32
#define KT 64
#define DC 64
#define NT 256

// ---- exact replication of numpy pairwise_sum for n=128 over squares ----
__device__ __forceinline__ float np_pw128_sq(const float* p) {
  float r[8];
#pragma unroll
  for (int j = 0; j < 8; ++j) r[j] = __fmul_rn(p[j], p[j]);
  for (int i = 8; i < 128; i += 8) {
#pragma unroll
    for (int j = 0; j < 8; ++j)
      r[j] = __fadd_rn(r[j], __fmul_rn(p[i + j], p[i + j]));
  }
  return __fadd_rn(__fadd_rn(__fadd_rn(r[0], r[1]), __fadd_rn(r[2], r[3])),
                   __fadd_rn(__fadd_rn(r[4], r[5]), __fadd_rn(r[6], r[7])));
}
__device__ __forceinline__ float np_pw256_sq(const float* p) {
  return __fadd_rn(np_pw128_sq(p), np_pw128_sq(p + 128));  // n=256: 128+128 split
}

// ---------------- kernel 1: ||e_k||^2, numpy-exact ----------------
__global__ __launch_bounds__(256) void vq_norms(const float* __restrict__ cb,
                                                float* __restrict__ Bk) {
  int k = blockIdx.x * 256 + threadIdx.x;   // one thread per code
  if (k < KK) Bk[k] = np_pw256_sq(cb + (size_t)k * DD);
}

// ---------------- kernel 2: distances + argmin + outputs ----------------
__global__ __launch_bounds__(256, 2) void vq_main(
    const float* __restrict__ z, const float* __restrict__ cb,
    const float* __restrict__ Bk, float* __restrict__ out,
    int* __restrict__ hist, float* __restrict__ loss_acc) {
  __shared__ float zt[MT][DD + 4];
  __shared__ float ct[KT][DC + 4];
  __shared__ float Arow[MT];
  __shared__ float Bs[KT];
  __shared__ float redD[MT][8];
  __shared__ int redI[MT][8];
  __shared__ int kwin[MT];

  const int t = threadIdx.x;
  const int n0 = blockIdx.x * MT;
  const int bimg = n0 >> 10;
  const int hw0 = n0 & 1023;
  const float* zb = z + (size_t)bimg * (DD * HW) + hw0;

  for (int li = t; li < MT * DD; li += NT) {
    int d = li >> 5, r = li & 31;
    zt[r][d] = zb[d * HW + r];
  }
  __syncthreads();
  if (t < MT) Arow[t] = np_pw256_sq(&zt[t][0]);  // numpy-exact ||z||^2

  const int rr = t & 31;
  const int kg = t >> 5;
  float best = 3.4e38f;
  int bidx = 0;

  for (int k0 = 0; k0 < KK; k0 += KT) {
    float acc[8];
#pragma unroll
    for (int i = 0; i < 8; ++i) acc[i] = 0.f;

    for (int dc = 0; dc < DD; dc += DC) {
      __syncthreads();
      for (int li = t; li < KT * (DC / 4); li += NT) {
        int kk = li >> 4;
        int fq = li & 15;
        float4 v = *(const float4*)(cb + (size_t)(k0 + kk) * DD + dc + (fq << 2));
        *(float4*)&ct[kk][fq << 2] = v;
      }
      if (dc == 0 && t < KT) Bs[t] = Bk[k0 + t];
      __syncthreads();
      // sequential ascending-d fmaf chain == OpenBLAS sgemm microkernel order
#pragma unroll
      for (int ds = 0; ds < DC; ds += 4) {
        float4 zv = *(const float4*)&zt[rr][dc + ds];
#pragma unroll
        for (int i = 0; i < 8; ++i) {
          float4 cv = *(const float4*)&ct[(kg << 3) + i][ds];
          acc[i] = fmaf(zv.x, cv.x, acc[i]);
          acc[i] = fmaf(zv.y, cv.y, acc[i]);
          acc[i] = fmaf(zv.z, cv.z, acc[i]);
          acc[i] = fmaf(zv.w, cv.w, acc[i]);
        }
      }
    }
    float A = Arow[rr];
#pragma unroll
    for (int i = 0; i < 8; ++i) {
      int c = (kg << 3) + i;
      float tmp = __fadd_rn(A, Bs[c]);                       // fl(A+B)
      float dist = __fsub_rn(tmp, __fmul_rn(2.f, acc[i]));   // fl(tmp - 2*dot)
      if (dist < best) { best = dist; bidx = k0 + c; }       // first-min wins
    }
  }

  redD[rr][kg] = best;
  redI[rr][kg] = bidx;
  __syncthreads();
  if (t < MT) {
    float bd = redD[t][0];
    int bi = redI[t][0];
#pragma unroll
    for (int j = 1; j < 8; ++j) {
      float dj = redD[t][j];
      int ij = redI[t][j];
      if (dj < bd || (dj == bd && ij < bi)) { bd = dj; bi = ij; }
    }
    kwin[t] = bi;
    atomicAdd(&hist[bi], 1);
    out[(size_t)NELEM + 1 + n0 + t] = (float)bi;   // indices chunk (fp32)
  }
  __syncthreads();

  float lsum = 0.f;
  for (int it = 0; it < MT; ++it) {
    int li = it * NT + t;
    int d = li >> 5, r = li & 31;
    float zq = cb[(size_t)kwin[r] * DD + d];
    float ze = zt[r][d];
    float diff = __fsub_rn(zq, ze);
    float st = __fadd_rn(ze, diff);                 // z_e + (z_q - z_e)
    out[(size_t)(bimg * DD + d) * HW + hw0 + r] = st;
    lsum = fmaf(diff, diff, lsum);
  }
#pragma unroll
  for (int off = 32; off > 0; off >>= 1) lsum += __shfl_down(lsum, off);
  if ((t & 63) == 0) atomicAdd(loss_acc, lsum);
}

// ---------------- kernel 3: vq_loss + perplexity ----------------
__global__ __launch_bounds__(256) void vq_final(const int* __restrict__ hist,
                                                const float* __restrict__ loss,
                                                float* __restrict__ out) {
  __shared__ float sred[256];
  int t = threadIdx.x;
  float s = 0.f;
  for (int k = t; k < KK; k += 256) {
    float p = (float)hist[k] * (1.f / 16384.f);
    s += p * logf(p + 1e-10f);
  }
  sred[t] = s;
  __syncthreads();
  for (int off = 128; off > 0; off >>= 1) {
    if (t < off) sred[t] += sred[t + off];
    __syncthreads();
  }
  if (t == 0) {
    float L = loss[0] / (float)NELEM;
    out[NELEM] = 1.25f * L;                     // codebook + 0.25*commitment
    out[(size_t)NELEM + 1 + NROWS] = expf(-sred[0]);
  }
}

extern "C" void kernel_launch(void* const* d_in, const int* in_sizes, int n_in,
                              void* d_out, int out_size, void* d_ws, size_t ws_size,
                              hipStream_t stream) {
  const float* z = (const float*)d_in[0];       // (16,256,32,32) fp32
  const float* cb = (const float*)d_in[1];      // (8192,256) fp32
  float* out = (float*)d_out;                   // FLOAT32: [z_q_st|loss|idx|perp]

  int* hist = (int*)d_ws;                       // 8192 ints
  float* loss = (float*)d_ws + 8192;            // 1 float
  float* Bk = (float*)d_ws + 8448;              // 8192 floats

  hipMemsetAsync(d_ws, 0, 8448 * sizeof(float), stream);
  vq_norms<<<KK / 256, 256, 0, stream>>>(cb, Bk);
  vq_main<<<NROWS / MT, NT, 0, stream>>>(z, cb, Bk, out, hist, loss);
  vq_final<<<1, 256, 0, stream>>>(hist, loss, out);
}

// Round 3
// 1105.081 us; speedup vs baseline: 2.7102x; 2.7102x over previous
//
#include <hip/hip_runtime.h>

#define DD 256
#define KK 8192
#define HW 1024
#define NROWS 16384
#define NELEM 4194304
#define MT 32        // rows per block
#define KT 512       // codes per k-tile (64 lanes x 8 codes)
#define NT 256

// ---- exact replication of numpy pairwise_sum (n=256) over squares ----
__device__ __forceinline__ float np_pw128_sq(const float* p) {
  float r[8];
#pragma unroll
  for (int j = 0; j < 8; ++j) r[j] = __fmul_rn(p[j], p[j]);
  for (int i = 8; i < 128; i += 8) {
#pragma unroll
    for (int j = 0; j < 8; ++j)
      r[j] = __fadd_rn(r[j], __fmul_rn(p[i + j], p[i + j]));
  }
  return __fadd_rn(__fadd_rn(__fadd_rn(r[0], r[1]), __fadd_rn(r[2], r[3])),
                   __fadd_rn(__fadd_rn(r[4], r[5]), __fadd_rn(r[6], r[7])));
}

// ---------------- kernel: ||e_k||^2, numpy-exact ----------------
__global__ __launch_bounds__(256) void vq_norms(const float* __restrict__ cb,
                                                float* __restrict__ Bk) {
  int k = blockIdx.x * 256 + threadIdx.x;
  const float* p = cb + (size_t)k * DD;
  Bk[k] = __fadd_rn(np_pw128_sq(p), np_pw128_sq(p + 128));
}

// ---------------- kernel: ||z_n||^2, numpy-exact (strided reads) ----------------
__global__ __launch_bounds__(256) void vq_arow(const float* __restrict__ z,
                                               float* __restrict__ Arow) {
  int n = blockIdx.x * 256 + threadIdx.x;      // 0..16383
  int bimg = n >> 10, hw = n & 1023;
  const float* zp = z + (size_t)bimg * DD * HW + hw;
  float h[2];
#pragma unroll
  for (int half = 0; half < 2; ++half) {
    float r[8];
#pragma unroll
    for (int j = 0; j < 8; ++j) {
      float v = zp[(size_t)(half * 128 + j) * HW];
      r[j] = __fmul_rn(v, v);
    }
    for (int i = 8; i < 128; i += 8) {
#pragma unroll
      for (int j = 0; j < 8; ++j) {
        float v = zp[(size_t)(half * 128 + i + j) * HW];
        r[j] = __fadd_rn(r[j], __fmul_rn(v, v));
      }
    }
    h[half] = __fadd_rn(__fadd_rn(__fadd_rn(r[0], r[1]), __fadd_rn(r[2], r[3])),
                        __fadd_rn(__fadd_rn(r[4], r[5]), __fadd_rn(r[6], r[7])));
  }
  Arow[n] = __fadd_rn(h[0], h[1]);
}

// ---------------- kernel: codebook transpose cbT[d][k] = cb[k][d] ----------------
__global__ __launch_bounds__(256) void vq_transpose(const float* __restrict__ cb,
                                                    float* __restrict__ cbT) {
  __shared__ float tile[64][65];
  int k0 = blockIdx.x * 64, d0 = blockIdx.y * 64;
  for (int li = threadIdx.x; li < 64 * 64; li += 256) {
    int kk = li >> 6, dd = li & 63;
    tile[kk][dd] = cb[(size_t)(k0 + kk) * DD + d0 + dd];
  }
  __syncthreads();
  for (int li = threadIdx.x; li < 64 * 64; li += 256) {
    int dd = li >> 6, kk = li & 63;
    cbT[(size_t)(d0 + dd) * KK + k0 + kk] = tile[kk][dd];
  }
}

// ---------------- main: dist + argmin + outputs ----------------
__global__ __launch_bounds__(256, 2) void vq_main(
    const float* __restrict__ z, const float* __restrict__ cbT,
    const float* __restrict__ cb, const float* __restrict__ Bk,
    const float* __restrict__ Arow, float* __restrict__ out,
    int* __restrict__ hist, float* __restrict__ loss_acc) {
  __shared__ float zt[MT][DD + 4];   // 33.3 KB, staged ONCE, kept for epilogue
  __shared__ float redD[MT][64];
  __shared__ int redI[MT][64];
  __shared__ int kwin[MT];

  const int t = threadIdx.x;
  const int n0 = blockIdx.x * MT;
  const int bimg = n0 >> 10, hw0 = n0 & 1023;
  const float* zb = z + (size_t)bimg * DD * HW + hw0;

  for (int li = t; li < MT * DD; li += NT) {
    int d = li >> 5, r = li & 31;
    zt[r][d] = zb[d * HW + r];
  }
  __syncthreads();

  const int rowg = t >> 6;   // 0..3  (wave id): 8 rows per thread
  const int cg = t & 63;     // lane: 8 consecutive codes per thread

  float Aj[8];
#pragma unroll
  for (int j = 0; j < 8; ++j) Aj[j] = Arow[n0 + rowg * 8 + j];

  float bestD[8];
  int bestI[8];
#pragma unroll
  for (int j = 0; j < 8; ++j) { bestD[j] = 3.4e38f; bestI[j] = 0; }

  for (int k0 = 0; k0 < KK; k0 += KT) {   // 16 k-tiles, NO barriers inside
    float acc[8][8];
#pragma unroll
    for (int j = 0; j < 8; ++j)
#pragma unroll
      for (int i = 0; i < 8; ++i) acc[j][i] = 0.f;

    const float* cp = cbT + k0 + cg * 8;  // lane-contiguous: coalesced 1KB/wave
#pragma unroll 2
    for (int d = 0; d < DD; d += 4) {
      float4 zv[8];
#pragma unroll
      for (int j = 0; j < 8; ++j)
        zv[j] = *(const float4*)&zt[rowg * 8 + j][d];   // wave-uniform broadcast
#pragma unroll
      for (int dd = 0; dd < 4; ++dd) {
        float4 cv0 = *(const float4*)(cp + (size_t)(d + dd) * KK);
        float4 cv1 = *(const float4*)(cp + (size_t)(d + dd) * KK + 4);
#pragma unroll
        for (int j = 0; j < 8; ++j) {
          float zs = ((const float*)&zv[j])[dd];  // d-ascending exact chain
          acc[j][0] = fmaf(zs, cv0.x, acc[j][0]);
          acc[j][1] = fmaf(zs, cv0.y, acc[j][1]);
          acc[j][2] = fmaf(zs, cv0.z, acc[j][2]);
          acc[j][3] = fmaf(zs, cv0.w, acc[j][3]);
          acc[j][4] = fmaf(zs, cv1.x, acc[j][4]);
          acc[j][5] = fmaf(zs, cv1.y, acc[j][5]);
          acc[j][6] = fmaf(zs, cv1.z, acc[j][6]);
          acc[j][7] = fmaf(zs, cv1.w, acc[j][7]);
        }
      }
    }
    // finalize tile: dist = fl(fl(A+B) - fl(2*dot)), strict < => first-min wins
    float4 Bv0 = *(const float4*)(Bk + k0 + cg * 8);
    float4 Bv1 = *(const float4*)(Bk + k0 + cg * 8 + 4);
    float Bv[8] = {Bv0.x, Bv0.y, Bv0.z, Bv0.w, Bv1.x, Bv1.y, Bv1.z, Bv1.w};
#pragma unroll
    for (int j = 0; j < 8; ++j) {
#pragma unroll
      for (int i = 0; i < 8; ++i) {       // i ascending => k ascending
        float tmp = __fadd_rn(Aj[j], Bv[i]);
        float dist = __fsub_rn(tmp, __fmul_rn(2.f, acc[j][i]));
        if (dist < bestD[j]) { bestD[j] = dist; bestI[j] = k0 + cg * 8 + i; }
      }
    }
  }

#pragma unroll
  for (int j = 0; j < 8; ++j) {
    redD[rowg * 8 + j][cg] = bestD[j];
    redI[rowg * 8 + j][cg] = bestI[j];
  }
  __syncthreads();
  if (t < MT) {
    float bd = redD[t][0];
    int bi = redI[t][0];
    for (int c = 1; c < 64; ++c) {
      float dj = redD[t][c];
      int ij = redI[t][c];
      if (dj < bd || (dj == bd && ij < bi)) { bd = dj; bi = ij; }  // np tie-break
    }
    kwin[t] = bi;
    atomicAdd(&hist[bi], 1);
    out[(size_t)NELEM + 1 + n0 + t] = (float)bi;
  }
  __syncthreads();

  // z_q gather + straight-through + loss (zt still holds z_e)
  float lsum = 0.f;
  for (int it = 0; it < MT; ++it) {
    int li = it * NT + t;
    int d = li >> 5, r = li & 31;
    float zq = cb[(size_t)kwin[r] * DD + d];
    float ze = zt[r][d];
    float diff = __fsub_rn(zq, ze);
    float st = __fadd_rn(ze, diff);
    out[(size_t)(bimg * DD + d) * HW + hw0 + r] = st;
    lsum = fmaf(diff, diff, lsum);
  }
#pragma unroll
  for (int off = 32; off > 0; off >>= 1) lsum += __shfl_down(lsum, off);
  if ((t & 63) == 0) atomicAdd(loss_acc, lsum);
}

// ---------------- finalize: vq_loss + perplexity ----------------
__global__ __launch_bounds__(256) void vq_final(const int* __restrict__ hist,
                                                const float* __restrict__ loss,
                                                float* __restrict__ out) {
  __shared__ float sred[256];
  int t = threadIdx.x;
  float s = 0.f;
  for (int k = t; k < KK; k += 256) {
    float p = (float)hist[k] * (1.f / 16384.f);
    s += p * logf(p + 1e-10f);
  }
  sred[t] = s;
  __syncthreads();
  for (int off = 128; off > 0; off >>= 1) {
    if (t < off) sred[t] += sred[t + off];
    __syncthreads();
  }
  if (t == 0) {
    float L = loss[0] / (float)NELEM;
    out[NELEM] = 1.25f * L;
    out[(size_t)NELEM + 1 + NROWS] = expf(-sred[0]);
  }
}

extern "C" void kernel_launch(void* const* d_in, const int* in_sizes, int n_in,
                              void* d_out, int out_size, void* d_ws, size_t ws_size,
                              hipStream_t stream) {
  const float* z = (const float*)d_in[0];   // (16,256,32,32) fp32
  const float* cb = (const float*)d_in[1];  // (8192,256) fp32
  float* out = (float*)d_out;               // fp32: [z_q_st | loss | idx | perp]

  int* hist = (int*)d_ws;                   // 8192 ints
  float* loss = (float*)d_ws + 8192;        // 1 float (+pad)
  float* Bk = (float*)d_ws + 8448;          // 8192
  float* Arow = (float*)d_ws + 16640;       // 16384
  float* cbT = (float*)d_ws + 33024;        // 2M floats (8 MB)

  hipMemsetAsync(d_ws, 0, 8448 * sizeof(float), stream);
  vq_transpose<<<dim3(KK / 64, DD / 64), 256, 0, stream>>>(cb, cbT);
  vq_norms<<<KK / 256, 256, 0, stream>>>(cb, Bk);
  vq_arow<<<NROWS / 256, 256, 0, stream>>>(z, Arow);
  vq_main<<<NROWS / MT, NT, 0, stream>>>(z, cbT, cb, Bk, Arow, out, hist, loss);
  vq_final<<<1, 256, 0, stream>>>(hist, loss, out);
}